// Round 1
// baseline (2757.721 us; speedup 1.0000x reference)
//
#include <hip/hip_runtime.h>
#include <math.h>

// Problem constants
#define QTOT   512
#define CDIM   256
#define HDIM   1024
#define NROWS  500000
#define NB     128
#define NTILES ((NROWS + NB - 1) / NB)   // 3907
#define LDB    264                       // bf16 row stride in LDS (16B-aligned, bank-friendly)
#define DELTA  2.0f

typedef short bf16x8 __attribute__((ext_vector_type(8)));
typedef float f32x4  __attribute__((ext_vector_type(4)));

__device__ __forceinline__ unsigned short bf16_rne(float f) {
  unsigned u = __float_as_uint(f);
  u += 0x7FFFu + ((u >> 16) & 1u);
  return (unsigned short)(u >> 16);
}
__device__ __forceinline__ unsigned bfp2(float a, float b) {
  return (unsigned)bf16_rne(a) | ((unsigned)bf16_rne(b) << 16);
}

// ---------------------------------------------------------------- K0: codes -> bf16(-2c)
__global__ void k_prep(const float* __restrict__ codes, unsigned short* __restrict__ a0) {
  int i = blockIdx.x * 256 + threadIdx.x;  // grid 512 covers 512*256
  a0[i] = bf16_rne(-2.0f * codes[i]);
}

// ---------------------------------------------------------------- K1: coarse bf16 distance, per-(q,tile) min
// key(q,n) = ||cb_n||^2 - 2 c_q . cb_n   (per-q const ||c||^2 dropped; argmin unchanged)
__global__ __launch_bounds__(256) void k_coarse(
    const unsigned short* __restrict__ a0,   // 512x256 bf16 of (-2c)
    const float* __restrict__ cb,            // 500000x256 fp32
    float* __restrict__ tileMin)             // 512 x NTILES float
{
  __shared__ unsigned short Ash[128 * LDB];
  __shared__ unsigned short Bsh[128 * LDB];
  __shared__ float c2sh[128];
  __shared__ float redf[128 * 2];

  const int tid  = threadIdx.x;
  const int lane = tid & 63;
  const int w    = tid >> 6;
  const int q0   = blockIdx.x * 128;   // 0..3
  const int nt   = blockIdx.y;         // 0..3906
  const int n0   = nt * NB;

  // stage A tile (bf16, already converted): 128 rows x 32 16B-units
#pragma unroll
  for (int it = 0; it < 16; ++it) {
    int i = it * 256 + tid;
    int row = i >> 5, u = i & 31;
    uint4 v = *(const uint4*)(a0 + (q0 + row) * CDIM + u * 8);
    *(uint4*)&Ash[row * LDB + u * 8] = v;
  }
  // stage B tile: fp32 load -> bf16 cvt -> LDS; fused ||cb||^2 via wave reduction
  // mapping: f = j*256+tid => row = 4j + wave (wave-uniform), lane = float4 col
#pragma unroll 4
  for (int j = 0; j < 32; ++j) {
    int f = j * 256 + tid;
    int row = f >> 6;
    int c4  = f & 63;
    int n   = n0 + row;
    float4 v = make_float4(0.f, 0.f, 0.f, 0.f);
    if (n < NROWS) v = *(const float4*)(cb + (size_t)n * CDIM + c4 * 4);
    float sq = v.x * v.x + v.y * v.y + v.z * v.z + v.w * v.w;
    uint2 p; p.x = bfp2(v.x, v.y); p.y = bfp2(v.z, v.w);
    *(uint2*)&Bsh[row * LDB + c4 * 4] = p;
#pragma unroll
    for (int s = 32; s; s >>= 1) sq += __shfl_xor(sq, s);
    if (lane == 0) c2sh[row] = (n < NROWS) ? sq : 1e30f;
  }
  __syncthreads();

  const int quad = lane >> 4;
  const int l15  = lane & 15;
  const int wq   = (w >> 1) * 64;  // wave q-half
  const int wn   = (w & 1) * 64;   // wave n-half  (4x4 frag grid per wave: 8 ds_read per 16 MFMA)

  f32x4 acc[4][4];
#pragma unroll
  for (int m = 0; m < 4; ++m)
#pragma unroll
    for (int j2 = 0; j2 < 4; ++j2) acc[m][j2] = (f32x4){0.f, 0.f, 0.f, 0.f};

#pragma unroll
  for (int ks = 0; ks < 8; ++ks) {
    const int kb = ks * 32 + quad * 8;
    bf16x8 a[4], b[4];
#pragma unroll
    for (int m = 0; m < 4; ++m)
      a[m] = *(const bf16x8*)&Ash[(wq + m * 16 + l15) * LDB + kb];
#pragma unroll
    for (int j2 = 0; j2 < 4; ++j2)
      b[j2] = *(const bf16x8*)&Bsh[(wn + j2 * 16 + l15) * LDB + kb];
#pragma unroll
    for (int m = 0; m < 4; ++m)
#pragma unroll
      for (int j2 = 0; j2 < 4; ++j2)
        acc[m][j2] = __builtin_amdgcn_mfma_f32_16x16x32_bf16(a[m], b[j2], acc[m][j2], 0, 0, 0);
  }

  // epilogue: per-q min over this block's 128 n
  float cadd[4];
#pragma unroll
  for (int j2 = 0; j2 < 4; ++j2) cadd[j2] = c2sh[wn + j2 * 16 + l15];

#pragma unroll
  for (int m = 0; m < 4; ++m) {
#pragma unroll
    for (int r = 0; r < 4; ++r) {
      float kk = 1e30f;
#pragma unroll
      for (int j2 = 0; j2 < 4; ++j2) kk = fminf(kk, acc[m][j2][r] + cadd[j2]);
#pragma unroll
      for (int s = 1; s < 16; s <<= 1) kk = fminf(kk, __shfl_xor(kk, s));
      if (l15 == 0) redf[(wq + m * 16 + quad * 4 + r) * 2 + (w & 1)] = kk;
    }
  }
  __syncthreads();
  if (tid < 128) {
    float v = fminf(redf[tid * 2], redf[tid * 2 + 1]);
    tileMin[(size_t)(q0 + tid) * NTILES + nt] = v;
  }
}

// ---------------------------------------------------------------- K2: exact refine + gather prev
__global__ __launch_bounds__(256) void k_refine(
    const float* __restrict__ codes, const float* __restrict__ cb,
    const float* __restrict__ tileMin, float* __restrict__ prev)
{
#define LCAP 96
  __shared__ float csh[256];
  __shared__ float red[256];
  __shared__ int   list[LCAP];
  __shared__ int   cnt;
  __shared__ double rd[256];
  __shared__ int    rn[256];

  const int q = blockIdx.x;
  const int tid = threadIdx.x;
  csh[tid] = codes[q * CDIM + tid];
  if (tid == 0) cnt = 0;
  const float* tm = tileMin + (size_t)q * NTILES;
  float lm = 1e30f;
  for (int t = tid; t < NTILES; t += 256) lm = fminf(lm, tm[t]);
  red[tid] = lm;
  __syncthreads();
  for (int s = 128; s; s >>= 1) {
    if (tid < s) red[tid] = fminf(red[tid], red[tid + s]);
    __syncthreads();
  }
  const float thresh = red[0] + DELTA;
  for (int t = tid; t < NTILES; t += 256)
    if (tm[t] <= thresh) { int p = atomicAdd(&cnt, 1); if (p < LCAP) list[p] = t; }
  __syncthreads();
  const int nl = min(cnt, LCAP);

  double bestK = 1e300; int bestN = 0x7FFFFFFF;
  for (int li = 0; li < nl; ++li) {
    const int t = list[li];
    const int row = tid >> 1, half = tid & 1;
    const int n = t * NB + row;
    if (n < NROWS) {
      const float* r = cb + (size_t)n * CDIM;
      double dot = 0.0, sq = 0.0;
      for (int u = half * 32; u < half * 32 + 32; ++u) {
        float4 cv = *(const float4*)(r + u * 4);
        dot += (double)cv.x * csh[u*4+0] + (double)cv.y * csh[u*4+1]
             + (double)cv.z * csh[u*4+2] + (double)cv.w * csh[u*4+3];
        sq  += (double)cv.x * cv.x + (double)cv.y * cv.y
             + (double)cv.z * cv.z + (double)cv.w * cv.w;
      }
      dot += __shfl_xor(dot, 1);
      sq  += __shfl_xor(sq, 1);
      double key = sq - 2.0 * dot;
      if (key < bestK || (key == bestK && n < bestN)) { bestK = key; bestN = n; }
    }
  }
  rd[tid] = bestK; rn[tid] = bestN;
  __syncthreads();
  for (int s = 128; s; s >>= 1) {
    if (tid < s) {
      if (rd[tid + s] < rd[tid] || (rd[tid + s] == rd[tid] && rn[tid + s] < rn[tid])) {
        rd[tid] = rd[tid + s]; rn[tid] = rn[tid + s];
      }
    }
    __syncthreads();
  }
  const int nstar = rn[0];
  prev[(size_t)q * CDIM + tid] = cb[(size_t)nstar * CDIM + tid];
}

// ---------------------------------------------------------------- K3: generic MLP GEMM
// out[q][n] = maybe_tanh( sum_k (A1+A2+A3)[q][k] * W[n][k] + bias[n] )
// block tile: 128q x 64n, K chunked by 256; wave tile 32q x 64n
__global__ __launch_bounds__(256) void k_gemm(
    const float* __restrict__ A1, const float* __restrict__ A2, const float* __restrict__ A3,
    const float* __restrict__ W, const float* __restrict__ bias, float* __restrict__ out,
    int Kdim, int Ntot, int do_tanh)
{
  __shared__ unsigned short Ash[128 * LDB];
  __shared__ unsigned short Wsh[64 * LDB];
  __shared__ float bsh[64];

  const int tid  = threadIdx.x;
  const int lane = tid & 63;
  const int w    = tid >> 6;
  const int quad = lane >> 4;
  const int l15  = lane & 15;
  const int q0   = blockIdx.x * 128;
  const int n0   = blockIdx.y * 64;

  if (tid < 64) bsh[tid] = bias[n0 + tid];

  f32x4 acc[2][4];
#pragma unroll
  for (int m = 0; m < 2; ++m)
#pragma unroll
    for (int j = 0; j < 4; ++j) acc[m][j] = (f32x4){0.f, 0.f, 0.f, 0.f};

  for (int kc = 0; kc < Kdim; kc += 256) {
    __syncthreads();
    // stage A chunk: 128 rows x 64 float4
#pragma unroll 4
    for (int it = 0; it < 32; ++it) {
      int i = it * 256 + tid;
      int row = i >> 6, c4 = i & 63;
      size_t gi = (size_t)(q0 + row) * Kdim + kc + c4 * 4;
      float4 v = *(const float4*)(A1 + gi);
      if (A2) { float4 u = *(const float4*)(A2 + gi); v.x += u.x; v.y += u.y; v.z += u.z; v.w += u.w; }
      if (A3) { float4 u = *(const float4*)(A3 + gi); v.x += u.x; v.y += u.y; v.z += u.z; v.w += u.w; }
      uint2 p; p.x = bfp2(v.x, v.y); p.y = bfp2(v.z, v.w);
      *(uint2*)&Ash[row * LDB + c4 * 4] = p;
    }
    // stage W chunk: 64 rows x 64 float4
#pragma unroll 4
    for (int it = 0; it < 16; ++it) {
      int i = it * 256 + tid;
      int row = i >> 6, c4 = i & 63;
      size_t gi = (size_t)(n0 + row) * Kdim + kc + c4 * 4;
      float4 v = *(const float4*)(W + gi);
      uint2 p; p.x = bfp2(v.x, v.y); p.y = bfp2(v.z, v.w);
      *(uint2*)&Wsh[row * LDB + c4 * 4] = p;
    }
    __syncthreads();
#pragma unroll
    for (int ks = 0; ks < 8; ++ks) {
      const int kb = ks * 32 + quad * 8;
      bf16x8 a[2], b[4];
#pragma unroll
      for (int m = 0; m < 2; ++m)
        a[m] = *(const bf16x8*)&Ash[(w * 32 + m * 16 + l15) * LDB + kb];
#pragma unroll
      for (int j = 0; j < 4; ++j)
        b[j] = *(const bf16x8*)&Wsh[(j * 16 + l15) * LDB + kb];
#pragma unroll
      for (int m = 0; m < 2; ++m)
#pragma unroll
        for (int j = 0; j < 4; ++j)
          acc[m][j] = __builtin_amdgcn_mfma_f32_16x16x32_bf16(a[m], b[j], acc[m][j], 0, 0, 0);
    }
  }

#pragma unroll
  for (int m = 0; m < 2; ++m)
#pragma unroll
    for (int j = 0; j < 4; ++j)
#pragma unroll
      for (int r = 0; r < 4; ++r) {
        int q = q0 + w * 32 + m * 16 + quad * 4 + r;
        int n = j * 16 + l15;
        float v = acc[m][j][r] + bsh[n];
        if (do_tanh) v = tanhf(v);
        out[(size_t)q * Ntot + n0 + n] = v;
      }
}

// ---------------------------------------------------------------- launch
extern "C" void kernel_launch(void* const* d_in, const int* in_sizes, int n_in,
                              void* d_out, int out_size, void* d_ws, size_t ws_size,
                              hipStream_t stream) {
  const float* codes = (const float*)d_in[0];
  const float* cb    = (const float*)d_in[1];
  const float* w_in  = (const float*)d_in[2];
  const float* b_in  = (const float*)d_in[3];
  const float* w_h1  = (const float*)d_in[4];
  const float* b_h1  = (const float*)d_in[5];
  const float* w_s2  = (const float*)d_in[6];
  const float* b_s2  = (const float*)d_in[7];
  const float* w_s3  = (const float*)d_in[8];
  const float* b_s3  = (const float*)d_in[9];
  const float* w_h2  = (const float*)d_in[10];
  const float* b_h2  = (const float*)d_in[11];
  const float* w_s1o = (const float*)d_in[12];
  const float* b_s1o = (const float*)d_in[13];
  const float* w_s2o = (const float*)d_in[14];
  const float* b_s2o = (const float*)d_in[15];
  const float* w_h3  = (const float*)d_in[16];
  const float* b_h3  = (const float*)d_in[17];
  const float* w_mu  = (const float*)d_in[18];
  const float* b_mu  = (const float*)d_in[19];
  const float* w_s   = (const float*)d_in[20];
  const float* b_s   = (const float*)d_in[21];
  float* out = (float*)d_out;

  char* ws = (char*)d_ws;
  unsigned short* a0 = (unsigned short*)ws;                      // 262,144 B
  float* tileMin = (float*)(ws + 262144);                        // 8,001,536 B
  float* prev    = (float*)(ws + 262144 + 8001536);              // 524,288 B
  float* acts    = (float*)(ws + 262144 + 8001536 + 524288);     // 8 x 2 MiB
  const int ACT = 512 * 1024;
  float* act_i  = acts + 0 * ACT;
  float* act_h1 = acts + 1 * ACT;
  float* act_s2 = acts + 2 * ACT;
  float* act_s3 = acts + 3 * ACT;
  float* act_h2 = acts + 4 * ACT;
  float* act_o1 = acts + 5 * ACT;
  float* act_o2 = acts + 6 * ACT;
  float* act_o3 = acts + 7 * ACT;

  hipLaunchKernelGGL(k_prep,   dim3(512),        dim3(256), 0, stream, codes, a0);
  hipLaunchKernelGGL(k_coarse, dim3(4, NTILES),  dim3(256), 0, stream, a0, cb, tileMin);
  hipLaunchKernelGGL(k_refine, dim3(512),        dim3(256), 0, stream, codes, cb, tileMin, prev);

  // MLP: i -> h1 -> {s2,s3,o1} -> h2(h1+s2) -> {o2(h2), o3(h2+s3)} -> mu/s(o1+o2+o3)
  hipLaunchKernelGGL(k_gemm, dim3(4, 16), dim3(256), 0, stream, prev,   (const float*)nullptr, (const float*)nullptr, w_in,  b_in,  act_i,  256,  1024, 1);
  hipLaunchKernelGGL(k_gemm, dim3(4, 16), dim3(256), 0, stream, act_i,  (const float*)nullptr, (const float*)nullptr, w_h1,  b_h1,  act_h1, 1024, 1024, 1);
  hipLaunchKernelGGL(k_gemm, dim3(4, 16), dim3(256), 0, stream, act_h1, (const float*)nullptr, (const float*)nullptr, w_s2,  b_s2,  act_s2, 1024, 1024, 1);
  hipLaunchKernelGGL(k_gemm, dim3(4, 16), dim3(256), 0, stream, act_h1, (const float*)nullptr, (const float*)nullptr, w_s3,  b_s3,  act_s3, 1024, 1024, 1);
  hipLaunchKernelGGL(k_gemm, dim3(4, 16), dim3(256), 0, stream, act_h1, (const float*)nullptr, (const float*)nullptr, w_s1o, b_s1o, act_o1, 1024, 1024, 1);
  hipLaunchKernelGGL(k_gemm, dim3(4, 16), dim3(256), 0, stream, act_h1, act_s2,                (const float*)nullptr, w_h2,  b_h2,  act_h2, 1024, 1024, 1);
  hipLaunchKernelGGL(k_gemm, dim3(4, 16), dim3(256), 0, stream, act_h2, (const float*)nullptr, (const float*)nullptr, w_s2o, b_s2o, act_o2, 1024, 1024, 1);
  hipLaunchKernelGGL(k_gemm, dim3(4, 16), dim3(256), 0, stream, act_h2, act_s3,                (const float*)nullptr, w_h3,  b_h3,  act_o3, 1024, 1024, 1);
  hipLaunchKernelGGL(k_gemm, dim3(4, 4),  dim3(256), 0, stream, act_o1, act_o2,                act_o3,                w_mu,  b_mu,  out,           1024, 256, 0);
  hipLaunchKernelGGL(k_gemm, dim3(4, 4),  dim3(256), 0, stream, act_o1, act_o2,                act_o3,                w_s,   b_s,   out + 131072,  1024, 256, 0);
}

// Round 3
// 1813.559 us; speedup vs baseline: 1.5206x; 1.5206x over previous
//
#include <hip/hip_runtime.h>
#include <math.h>

// Problem constants
#define QTOT   512
#define CDIM   256
#define HDIM   1024
#define NROWS  500000
#define NB     128
#define NTILES ((NROWS + NB - 1) / NB)   // 3907
#define LDB    264                       // bf16 row stride in LDS
#define DELTA  2.0f

typedef short bf16x8 __attribute__((ext_vector_type(8)));
typedef float f32x4  __attribute__((ext_vector_type(4)));

__device__ __forceinline__ unsigned short bf16_rne(float f) {
  unsigned u = __float_as_uint(f);
  u += 0x7FFFu + ((u >> 16) & 1u);
  return (unsigned short)(u >> 16);
}
__device__ __forceinline__ unsigned bfp2(float a, float b) {
  return (unsigned)bf16_rne(a) | ((unsigned)bf16_rne(b) << 16);
}

// ---------------------------------------------------------------- K0: codes -> bf16(-2c), MFMA-frag swizzled
// frag layout: [qb(4)][m(8)][ks(8)][lane(64)][8 bf16]; lane = quad*16 + l15
// lane l of frag (qb,m,ks) holds A[q = qb*128 + m*16 + (l&15)][k = ks*32 + (l>>4)*8 + off]
__global__ void k_prep(const float* __restrict__ codes, unsigned short* __restrict__ a0s) {
  int q = blockIdx.x, k = threadIdx.x;
  float v = -2.0f * codes[q * CDIM + k];
  int qb = q >> 7, row = q & 127, m = row >> 4, l15 = row & 15;
  int ks = k >> 5, kin = k & 31, quad = kin >> 3, off = kin & 7;
  int lane = quad * 16 + l15;
  a0s[(((qb * 8 + m) * 8 + ks) * 64 + lane) * 8 + off] = bf16_rne(v);
}

// ---------------------------------------------------------------- K1: coarse bf16 distance, per-(q,tile) min
// key(q,n) = ||cb_n||^2 - 2 c_q . cb_n  (per-q ||c||^2 dropped; argmin unchanged)
// grid: 1-D 15628 blocks; swizzled so the 4 q-siblings of one nt share an XCD (L2 reuse)
__global__ __launch_bounds__(256, 2) void k_coarse(
    const unsigned short* __restrict__ a0s,
    const float* __restrict__ cb,
    float* __restrict__ tileMin)
{
  __shared__ unsigned short Bsh[128 * LDB];   // 67584 B
  __shared__ float c2sh[128];
  __shared__ float redf[128 * 2];

  const int tid  = threadIdx.x;
  const int lane = tid & 63;
  const int w    = tid >> 6;
  const int quad = lane >> 4;
  const int l15  = lane & 15;

  // swizzle: siblings (same nt, qb=0..3) have bids differing by 8 -> same XCD (round-robin heuristic)
  int bid = blockIdx.x;
  int qb, nt;
  if (bid < 15616) { int c = bid & 7; qb = (bid >> 3) & 3; nt = (bid >> 5) * 8 + c; }
  else             { int r = bid - 15616; nt = 3904 + (r >> 2); qb = r & 3; }
  const int n0 = nt * NB;

  const int wq = (w >> 1) * 64;  // wave q-half within 128-q chunk
  const int wn = (w & 1) * 64;   // wave n-half

  // A fragments direct from global (L2-resident 256 KB), coalesced 16B/lane
  bf16x8 afr[4][8];
  {
    const int mg0 = (w >> 1) * 4;
    const unsigned short* base = a0s + (size_t)(qb * 8 + mg0) * 8 * 64 * 8 + lane * 8;
#pragma unroll
    for (int m = 0; m < 4; ++m)
#pragma unroll
      for (int ks = 0; ks < 8; ++ks)
        afr[m][ks] = *(const bf16x8*)(base + (m * 8 + ks) * 64 * 8);
  }

  // stage B tile: fp32 -> bf16 -> LDS; fused ||cb||^2 wave-reduction
#pragma unroll 4
  for (int j = 0; j < 32; ++j) {
    int f = j * 256 + tid;
    int row = f >> 6;
    int c4  = f & 63;
    int n   = n0 + row;
    float4 v = make_float4(0.f, 0.f, 0.f, 0.f);
    if (n < NROWS) v = *(const float4*)(cb + (size_t)n * CDIM + c4 * 4);
    float sq = v.x * v.x + v.y * v.y + v.z * v.z + v.w * v.w;
    uint2 p; p.x = bfp2(v.x, v.y); p.y = bfp2(v.z, v.w);
    *(uint2*)&Bsh[row * LDB + c4 * 4] = p;
#pragma unroll
    for (int s = 32; s; s >>= 1) sq += __shfl_xor(sq, s);
    if (lane == 0) c2sh[row] = (n < NROWS) ? sq : 1e30f;
  }
  __syncthreads();

  f32x4 acc[4][4];
#pragma unroll
  for (int m = 0; m < 4; ++m)
#pragma unroll
    for (int j2 = 0; j2 < 4; ++j2) acc[m][j2] = (f32x4){0.f, 0.f, 0.f, 0.f};

#pragma unroll
  for (int ks = 0; ks < 8; ++ks) {
    const int kb = ks * 32 + quad * 8;
    bf16x8 b[4];
#pragma unroll
    for (int j2 = 0; j2 < 4; ++j2)
      b[j2] = *(const bf16x8*)&Bsh[(wn + j2 * 16 + l15) * LDB + kb];
#pragma unroll
    for (int m = 0; m < 4; ++m)
#pragma unroll
      for (int j2 = 0; j2 < 4; ++j2)
        acc[m][j2] = __builtin_amdgcn_mfma_f32_16x16x32_bf16(afr[m][ks], b[j2], acc[m][j2], 0, 0, 0);
  }

  // epilogue: per-q min over this tile's 128 n
  float cadd[4];
#pragma unroll
  for (int j2 = 0; j2 < 4; ++j2) cadd[j2] = c2sh[wn + j2 * 16 + l15];

#pragma unroll
  for (int m = 0; m < 4; ++m) {
#pragma unroll
    for (int r = 0; r < 4; ++r) {
      float kk = 1e30f;
#pragma unroll
      for (int j2 = 0; j2 < 4; ++j2) kk = fminf(kk, acc[m][j2][r] + cadd[j2]);
#pragma unroll
      for (int s = 1; s < 16; s <<= 1) kk = fminf(kk, __shfl_xor(kk, s));
      if (l15 == 0) redf[(wq + m * 16 + quad * 4 + r) * 2 + (w & 1)] = kk;
    }
  }
  __syncthreads();
  if (tid < 128) {
    float v = fminf(redf[tid * 2], redf[tid * 2 + 1]);
    tileMin[(size_t)(qb * 128 + tid) * NTILES + nt] = v;
  }
}

// ---------------------------------------------------------------- K2: exact refine + gather prev
__global__ __launch_bounds__(256) void k_refine(
    const float* __restrict__ codes, const float* __restrict__ cb,
    const float* __restrict__ tileMin, float* __restrict__ prev)
{
#define LCAP 96
  __shared__ float csh[256];
  __shared__ float red[256];
  __shared__ int   list[LCAP];
  __shared__ int   cnt;
  __shared__ double rd[256];
  __shared__ int    rn[256];

  const int q = blockIdx.x;
  const int tid = threadIdx.x;
  csh[tid] = codes[q * CDIM + tid];
  if (tid == 0) cnt = 0;
  const float* tm = tileMin + (size_t)q * NTILES;
  float lm = 1e30f;
  for (int t = tid; t < NTILES; t += 256) lm = fminf(lm, tm[t]);
  red[tid] = lm;
  __syncthreads();
  for (int s = 128; s; s >>= 1) {
    if (tid < s) red[tid] = fminf(red[tid], red[tid + s]);
    __syncthreads();
  }
  const float thresh = red[0] + DELTA;
  for (int t = tid; t < NTILES; t += 256)
    if (tm[t] <= thresh) { int p = atomicAdd(&cnt, 1); if (p < LCAP) list[p] = t; }
  __syncthreads();
  const int nl = min(cnt, LCAP);

  double bestK = 1e300; int bestN = 0x7FFFFFFF;
  for (int li = 0; li < nl; ++li) {
    const int t = list[li];
    const int row = tid >> 1, half = tid & 1;
    const int n = t * NB + row;
    if (n < NROWS) {
      const float* r = cb + (size_t)n * CDIM;
      double dot = 0.0, sq = 0.0;
      for (int u = half * 32; u < half * 32 + 32; ++u) {
        float4 cv = *(const float4*)(r + u * 4);
        dot += (double)cv.x * csh[u*4+0] + (double)cv.y * csh[u*4+1]
             + (double)cv.z * csh[u*4+2] + (double)cv.w * csh[u*4+3];
        sq  += (double)cv.x * cv.x + (double)cv.y * cv.y
             + (double)cv.z * cv.z + (double)cv.w * cv.w;
      }
      dot += __shfl_xor(dot, 1);
      sq  += __shfl_xor(sq, 1);
      double key = sq - 2.0 * dot;
      if (key < bestK || (key == bestK && n < bestN)) { bestK = key; bestN = n; }
    }
  }
  rd[tid] = bestK; rn[tid] = bestN;
  __syncthreads();
  for (int s = 128; s; s >>= 1) {
    if (tid < s) {
      if (rd[tid + s] < rd[tid] || (rd[tid + s] == rd[tid] && rn[tid + s] < rn[tid])) {
        rd[tid] = rd[tid + s]; rn[tid] = rn[tid + s];
      }
    }
    __syncthreads();
  }
  const int nstar = rn[0];
  prev[(size_t)q * CDIM + tid] = cb[(size_t)nstar * CDIM + tid];
}

// ---------------------------------------------------------------- K3: MLP GEMM (up to 3 jobs via blockIdx.z)
struct Job {
  const float* A1; const float* A2; const float* A3;
  const float* W;  const float* bias; float* out;
};

__global__ __launch_bounds__(256) void k_gemm(
    Job j0, Job j1, Job j2, int Kdim, int Ntot, int do_tanh)
{
  __shared__ unsigned short Ash[128 * LDB];
  __shared__ unsigned short Wsh[64 * LDB];
  __shared__ float bsh[64];

  const Job jb = (blockIdx.z == 0) ? j0 : ((blockIdx.z == 1) ? j1 : j2);
  const float* __restrict__ A1 = jb.A1;
  const float* __restrict__ A2 = jb.A2;
  const float* __restrict__ A3 = jb.A3;
  const float* __restrict__ W  = jb.W;

  const int tid  = threadIdx.x;
  const int lane = tid & 63;
  const int w    = tid >> 6;
  const int quad = lane >> 4;
  const int l15  = lane & 15;
  const int q0   = blockIdx.x * 128;
  const int n0   = blockIdx.y * 64;

  if (tid < 64) bsh[tid] = jb.bias[n0 + tid];

  f32x4 acc[2][4];
#pragma unroll
  for (int m = 0; m < 2; ++m)
#pragma unroll
    for (int j = 0; j < 4; ++j) acc[m][j] = (f32x4){0.f, 0.f, 0.f, 0.f};

  for (int kc = 0; kc < Kdim; kc += 256) {
    __syncthreads();
#pragma unroll 4
    for (int it = 0; it < 32; ++it) {
      int i = it * 256 + tid;
      int row = i >> 6, c4 = i & 63;
      size_t gi = (size_t)(q0 + row) * Kdim + kc + c4 * 4;
      float4 v = *(const float4*)(A1 + gi);
      if (A2) { float4 u = *(const float4*)(A2 + gi); v.x += u.x; v.y += u.y; v.z += u.z; v.w += u.w; }
      if (A3) { float4 u = *(const float4*)(A3 + gi); v.x += u.x; v.y += u.y; v.z += u.z; v.w += u.w; }
      uint2 p; p.x = bfp2(v.x, v.y); p.y = bfp2(v.z, v.w);
      *(uint2*)&Ash[row * LDB + c4 * 4] = p;
    }
#pragma unroll 4
    for (int it = 0; it < 16; ++it) {
      int i = it * 256 + tid;
      int row = i >> 6, c4 = i & 63;
      size_t gi = (size_t)(n0 + row) * Kdim + kc + c4 * 4;
      float4 v = *(const float4*)(W + gi);
      uint2 p; p.x = bfp2(v.x, v.y); p.y = bfp2(v.z, v.w);
      *(uint2*)&Wsh[row * LDB + c4 * 4] = p;
    }
    __syncthreads();
#pragma unroll
    for (int ks = 0; ks < 8; ++ks) {
      const int kb = ks * 32 + quad * 8;
      bf16x8 a[2], b[4];
#pragma unroll
      for (int m = 0; m < 2; ++m)
        a[m] = *(const bf16x8*)&Ash[(w * 32 + m * 16 + l15) * LDB + kb];
#pragma unroll
      for (int j = 0; j < 4; ++j)
        b[j] = *(const bf16x8*)&Wsh[(j * 16 + l15) * LDB + kb];
#pragma unroll
      for (int m = 0; m < 2; ++m)
#pragma unroll
        for (int j = 0; j < 4; ++j)
          acc[m][j] = __builtin_amdgcn_mfma_f32_16x16x32_bf16(a[m], b[j], acc[m][j], 0, 0, 0);
    }
  }

#pragma unroll
  for (int m = 0; m < 2; ++m)
#pragma unroll
    for (int j = 0; j < 4; ++j)
#pragma unroll
      for (int r = 0; r < 4; ++r) {
        int q = q0 + w * 32 + m * 16 + quad * 4 + r;
        int n = j * 16 + l15;
        float v = acc[m][j][r] + bsh[n];
        if (do_tanh) v = tanhf(v);
        jb.out[(size_t)q * Ntot + n0 + n] = v;
      }
}

// ---------------------------------------------------------------- launch
extern "C" void kernel_launch(void* const* d_in, const int* in_sizes, int n_in,
                              void* d_out, int out_size, void* d_ws, size_t ws_size,
                              hipStream_t stream) {
  const float* codes = (const float*)d_in[0];
  const float* cb    = (const float*)d_in[1];
  const float* w_in  = (const float*)d_in[2];
  const float* b_in  = (const float*)d_in[3];
  const float* w_h1  = (const float*)d_in[4];
  const float* b_h1  = (const float*)d_in[5];
  const float* w_s2  = (const float*)d_in[6];
  const float* b_s2  = (const float*)d_in[7];
  const float* w_s3  = (const float*)d_in[8];
  const float* b_s3  = (const float*)d_in[9];
  const float* w_h2  = (const float*)d_in[10];
  const float* b_h2  = (const float*)d_in[11];
  const float* w_s1o = (const float*)d_in[12];
  const float* b_s1o = (const float*)d_in[13];
  const float* w_s2o = (const float*)d_in[14];
  const float* b_s2o = (const float*)d_in[15];
  const float* w_h3  = (const float*)d_in[16];
  const float* b_h3  = (const float*)d_in[17];
  const float* w_mu  = (const float*)d_in[18];
  const float* b_mu  = (const float*)d_in[19];
  const float* w_s   = (const float*)d_in[20];
  const float* b_s   = (const float*)d_in[21];
  float* out = (float*)d_out;

  char* ws = (char*)d_ws;
  unsigned short* a0s = (unsigned short*)ws;                     // 262,144 B
  float* tileMin = (float*)(ws + 262144);                        // 8,001,536 B
  float* prev    = (float*)(ws + 262144 + 8001536);              // 524,288 B
  float* acts    = (float*)(ws + 262144 + 8001536 + 524288);     // 8 x 2 MiB
  const int ACT = 512 * 1024;
  float* act_i  = acts + 0 * ACT;
  float* act_h1 = acts + 1 * ACT;
  float* act_s2 = acts + 2 * ACT;
  float* act_s3 = acts + 3 * ACT;
  float* act_h2 = acts + 4 * ACT;
  float* act_o1 = acts + 5 * ACT;
  float* act_o2 = acts + 6 * ACT;
  float* act_o3 = acts + 7 * ACT;

  hipLaunchKernelGGL(k_prep,   dim3(512),         dim3(256), 0, stream, codes, a0s);
  hipLaunchKernelGGL(k_coarse, dim3(4 * NTILES),  dim3(256), 0, stream, a0s, cb, tileMin);
  hipLaunchKernelGGL(k_refine, dim3(512),         dim3(256), 0, stream, codes, cb, tileMin, prev);

  const float* NUL = nullptr;
  Job in_j  = { prev,   NUL,    NUL,    w_in,  b_in,  act_i  };
  Job h1_j  = { act_i,  NUL,    NUL,    w_h1,  b_h1,  act_h1 };
  Job s2_j  = { act_h1, NUL,    NUL,    w_s2,  b_s2,  act_s2 };
  Job s3_j  = { act_h1, NUL,    NUL,    w_s3,  b_s3,  act_s3 };
  Job o1_j  = { act_h1, NUL,    NUL,    w_s1o, b_s1o, act_o1 };
  Job h2_j  = { act_h1, act_s2, NUL,    w_h2,  b_h2,  act_h2 };
  Job o2_j  = { act_h2, NUL,    NUL,    w_s2o, b_s2o, act_o2 };
  Job o3_j  = { act_h2, act_s3, NUL,    w_h3,  b_h3,  act_o3 };
  Job mu_j  = { act_o1, act_o2, act_o3, w_mu,  b_mu,  out            };
  Job ls_j  = { act_o1, act_o2, act_o3, w_s,   b_s,   out + 131072   };

  hipLaunchKernelGGL(k_gemm, dim3(4, 16, 1), dim3(256), 0, stream, in_j, in_j, in_j, 256,  1024, 1);
  hipLaunchKernelGGL(k_gemm, dim3(4, 16, 1), dim3(256), 0, stream, h1_j, h1_j, h1_j, 1024, 1024, 1);
  hipLaunchKernelGGL(k_gemm, dim3(4, 16, 3), dim3(256), 0, stream, s2_j, s3_j, o1_j, 1024, 1024, 1);
  hipLaunchKernelGGL(k_gemm, dim3(4, 16, 1), dim3(256), 0, stream, h2_j, h2_j, h2_j, 1024, 1024, 1);
  hipLaunchKernelGGL(k_gemm, dim3(4, 16, 2), dim3(256), 0, stream, o2_j, o3_j, o3_j, 1024, 1024, 1);
  hipLaunchKernelGGL(k_gemm, dim3(4, 4, 2),  dim3(256), 0, stream, mu_j, ls_j, ls_j, 1024, 256,  0);
}